// Round 1
// baseline (523.747 us; speedup 1.0000x reference)
//
#include <hip/hip_runtime.h>

// VQ-VAE VectorQuantizer forward: fp32 baseline.
// z: (32,64,64,64) NCHW fp32; codebook: (1024,64) fp32.
// d_out: [0] = loss, [1..] = z_q_ste in NCHW (== codebook[argmin] numerically).

#define CB_N   1024
#define CDIM   64
#define HWDIM  4096          // H*W = 64*64
#define NBATCH 32
#define NQ     (NBATCH * HWDIM)   // 131072 query vectors
#define CHW    (CDIM * HWDIM)     // 262144
#define TOTAL_ELEMS 8388608.0f    // B*C*H*W

// ---------------- prep: codebook row norms + zero the loss accumulator ------
__global__ void vq_prep(const float* __restrict__ cb,
                        float* __restrict__ norms,
                        float* __restrict__ loss_acc) {
    int j = blockIdx.x * blockDim.x + threadIdx.x;
    if (j == 0) loss_acc[0] = 0.0f;
    if (j < CB_N) {
        const float* r = cb + j * CDIM;
        float s0 = 0.f, s1 = 0.f, s2 = 0.f, s3 = 0.f;
        #pragma unroll
        for (int c = 0; c < CDIM; c += 4) {
            s0 = fmaf(r[c + 0], r[c + 0], s0);
            s1 = fmaf(r[c + 1], r[c + 1], s1);
            s2 = fmaf(r[c + 2], r[c + 2], s2);
            s3 = fmaf(r[c + 3], r[c + 3], s3);
        }
        norms[j] = (s0 + s1) + (s2 + s3);
    }
}

// ---------------- main: one wave (64 lanes) per 64 consecutive queries ------
// Queries n = wave*64 + lane. n = b*4096 + hw, so a wave never straddles b.
// Codebook rows are wave-uniform reads -> compiler emits s_load (scalar cache),
// which dual-issues against the 64 v_fma per row.
__global__ __launch_bounds__(256, 2) void vq_main(
        const float* __restrict__ z,
        const float* __restrict__ cb,
        const float* __restrict__ norms,
        float* __restrict__ out,        // d_out base; out[0] written by vq_final
        float* __restrict__ loss_acc) {
    const int gtid = blockIdx.x * blockDim.x + threadIdx.x;
    const int wave = gtid >> 6;
    const int lane = threadIdx.x & 63;
    const int n    = wave * 64 + lane;
    const int b    = n >> 12;          // n / 4096
    const int hw   = n & 4095;

    // Load this lane's z vector (stride HWDIM floats; coalesced across lanes).
    const float* zp = z + (size_t)b * CHW + hw;
    float zr[CDIM];
    #pragma unroll
    for (int c = 0; c < CDIM; ++c) zr[c] = zp[(size_t)c * HWDIM];

    // Argmin over codes of d = ||e||^2 - 2 z.e   (||z||^2 constant per query)
    float dmin = 3.4e38f;
    int   jmin = 0;
    for (int j = 0; j < CB_N; ++j) {
        const float* __restrict__ r = cb + j * CDIM;   // wave-uniform -> s_load
        float a0 = 0.f, a1 = 0.f, a2 = 0.f, a3 = 0.f;
        #pragma unroll
        for (int c = 0; c < CDIM; c += 4) {
            a0 = fmaf(r[c + 0], zr[c + 0], a0);
            a1 = fmaf(r[c + 1], zr[c + 1], a1);
            a2 = fmaf(r[c + 2], zr[c + 2], a2);
            a3 = fmaf(r[c + 3], zr[c + 3], a3);
        }
        const float dot = (a0 + a1) + (a2 + a3);
        const float d   = fmaf(-2.0f, dot, norms[j]);
        if (d < dmin) { dmin = d; jmin = j; }   // strict < == first-min (jnp.argmin)
    }

    // Epilogue: gather winning code (float4, L2-hot), write NCHW, loss partial.
    const float4* __restrict__ q4 = (const float4*)(cb + (size_t)jmin * CDIM);
    float* op = out + 1 + (size_t)b * CHW + hw;
    float lsum = 0.f;
    #pragma unroll
    for (int c4 = 0; c4 < CDIM / 4; ++c4) {
        const float4 v = q4[c4];
        const int cbase = c4 * 4;
        float d0 = v.x - zr[cbase + 0];
        float d1 = v.y - zr[cbase + 1];
        float d2 = v.z - zr[cbase + 2];
        float d3 = v.w - zr[cbase + 3];
        lsum = fmaf(d0, d0, lsum);
        lsum = fmaf(d1, d1, lsum);
        lsum = fmaf(d2, d2, lsum);
        lsum = fmaf(d3, d3, lsum);
        op[(size_t)(cbase + 0) * HWDIM] = v.x;
        op[(size_t)(cbase + 1) * HWDIM] = v.y;
        op[(size_t)(cbase + 2) * HWDIM] = v.z;
        op[(size_t)(cbase + 3) * HWDIM] = v.w;
    }

    // Wave-level reduction of loss partial, one atomic per wave.
    #pragma unroll
    for (int off = 32; off > 0; off >>= 1)
        lsum += __shfl_down(lsum, off, 64);
    if (lane == 0) atomicAdd(loss_acc, lsum);
}

// ---------------- finalize: scalar loss ------------------------------------
__global__ void vq_final(const float* __restrict__ loss_acc,
                         float* __restrict__ out) {
    // loss = codebook_loss + 0.25 * commitment_loss = 1.25 * mean((z_q - z)^2)
    out[0] = 1.25f * loss_acc[0] / TOTAL_ELEMS;
}

extern "C" void kernel_launch(void* const* d_in, const int* in_sizes, int n_in,
                              void* d_out, int out_size, void* d_ws, size_t ws_size,
                              hipStream_t stream) {
    const float* z  = (const float*)d_in[0];
    const float* cb = (const float*)d_in[1];
    float* out      = (float*)d_out;

    float* loss_acc = (float*)d_ws;            // 1 float
    float* norms    = (float*)d_ws + 16;       // 1024 floats, 64B-aligned

    vq_prep<<<dim3(CB_N / 256), dim3(256), 0, stream>>>(cb, norms, loss_acc);

    const int waves  = NQ / 64;                // 2048
    const int blocks = waves / 4;              // 512 blocks of 256 threads
    vq_main<<<dim3(blocks), dim3(256), 0, stream>>>(z, cb, norms, out, loss_acc);

    vq_final<<<dim3(1), dim3(1), 0, stream>>>(loss_acc, out);
}

// Round 2
// 261.922 us; speedup vs baseline: 1.9996x; 1.9996x over previous
//
#include <hip/hip_runtime.h>

// VQ-VAE VectorQuantizer: bf16 split-MFMA distance + exact fp32 fallback.
// z: (32,64,64,64) NCHW fp32; codebook: (1024,64) fp32.
// d_out: [0]=loss, [1..]=z_q (NCHW).

#define CB_N   1024
#define KDIM   64
#define HWD    4096
#define CHW    (KDIM * HWD)
#define NQ     131072
#define TOTALF 8388608.0f
#define TAU    3.0e-3f
#define FCAP   16384

typedef __attribute__((ext_vector_type(8))) short  short8;
typedef __attribute__((ext_vector_type(4))) float  f32x4;

__device__ __forceinline__ unsigned short bf16_rne(float f) {
    union { float f; unsigned u; } c; c.f = f;
    return (unsigned short)((c.u + 0x7FFFu + ((c.u >> 16) & 1u)) >> 16);
}
__device__ __forceinline__ float bf16_tof(unsigned short h) {
    union { unsigned u; float f; } c; c.u = ((unsigned)h) << 16; return c.f;
}

// ---------- ws layout (byte offsets) ----------
// 0:    loss_acc (float)
// 4:    flag_cnt (int)
// 8:    done_cnt (int)
// 128:  norms    f32[1024]                     (4 KB)
// 4224: cbh      u16[1024*64]                  (128 KB)
// 135296: cbl    u16[1024*64]                  (128 KB)
// 266368: flag_q   i32[FCAP]
// 331904: flag_m1  f32[FCAP]
// 397440: flag_idx i32[FCAP]   (total ~463 KB)

// ---------------- prep: split codebook to bf16 hi/lo, norms, zero counters --
__global__ void vq_prep(const float* __restrict__ cb,
                        float* __restrict__ norms,
                        unsigned short* __restrict__ cbh,
                        unsigned short* __restrict__ cbl,
                        float* __restrict__ loss_acc,
                        int* __restrict__ flag_cnt,
                        int* __restrict__ done_cnt) {
    int j = blockIdx.x * 256 + threadIdx.x;
    if (j == 0) *loss_acc = 0.0f;
    if (j == 1) *flag_cnt = 0;
    if (j == 2) *done_cnt = 0;
    if (j < CB_N) {
        const float* r = cb + j * KDIM;
        float s = 0.0f;
        #pragma unroll
        for (int k = 0; k < KDIM; ++k) {
            float v = r[k];
            s = fmaf(v, v, s);
            unsigned short h = bf16_rne(v);
            cbh[j * KDIM + k] = h;
            cbl[j * KDIM + k] = bf16_rne(v - bf16_tof(h));
        }
        norms[j] = s;
    }
}

// ---------------- main: 1 wave = 64 queries x all 1024 codes via MFMA -------
__global__ __launch_bounds__(256, 2) void vq_main(
        const float* __restrict__ z,
        const float* __restrict__ cb,
        const unsigned short* __restrict__ cbh,
        const unsigned short* __restrict__ cbl,
        const float* __restrict__ norms,
        float* __restrict__ out,
        float* __restrict__ loss_acc,
        int* __restrict__ flag_q,
        float* __restrict__ flag_m1,
        int* __restrict__ flag_idx,
        int* __restrict__ flag_cnt) {
    __shared__ int   idx_s[4][64];
    __shared__ float zn_s[4][64];

    const int w    = threadIdx.x >> 6;
    const int lane = threadIdx.x & 63;
    const int quad = lane >> 4;
    const int l16  = lane & 15;
    const int gw   = blockIdx.x * 4 + w;
    const int qb   = gw * 64;                  // 64 queries per wave, same b
    const int b    = qb >> 12;
    const int hw0  = qb & 4095;

    // ---- stage A-fragments: z -> (-2z) split hi/lo, plus ||z||^2 partials
    // A layout: lane holds A[m=l16][k=quad*8+j]; query = t*16 + l16.
    const float* zbase = z + (size_t)b * CHW + hw0;
    short8 ah[4][2], al[4][2];
    float znp[4] = {0.f, 0.f, 0.f, 0.f};
    #pragma unroll
    for (int t = 0; t < 4; ++t) {
        #pragma unroll
        for (int ks = 0; ks < 2; ++ks) {
            #pragma unroll
            for (int j = 0; j < 8; ++j) {
                float v = zbase[(size_t)(ks * 32 + quad * 8 + j) * HWD + t * 16 + l16];
                znp[t] = fmaf(v, v, znp[t]);
                float s = -2.0f * v;
                unsigned short h = bf16_rne(s);
                ah[t][ks][j] = (short)h;
                al[t][ks][j] = (short)bf16_rne(s - bf16_tof(h));
            }
        }
    }
    // reduce znorm over quads (lanes differing in bits 4,5; l16 preserved)
    #pragma unroll
    for (int t = 0; t < 4; ++t) {
        znp[t] += __shfl_xor(znp[t], 16, 64);
        znp[t] += __shfl_xor(znp[t], 32, 64);
    }
    if (lane < 16) {
        #pragma unroll
        for (int t = 0; t < 4; ++t) zn_s[w][t * 16 + lane] = znp[t];
    }

    // ---- main loop over 64 code-tiles of 16, double-buffered B-frags
    float m1[4][4], m2[4][4];
    int   i1[4][4];
    #pragma unroll
    for (int t = 0; t < 4; ++t)
        #pragma unroll
        for (int r = 0; r < 4; ++r) { m1[t][r] = 3.4e38f; m2[t][r] = 3.4e38f; i1[t][r] = 0; }

    const int eoff = l16 * KDIM + quad * 8;    // element offset within tile n0=0
    short8 bh0 = *(const short8*)(cbh + eoff);
    short8 bh1 = *(const short8*)(cbh + eoff + 32);
    short8 bl0 = *(const short8*)(cbl + eoff);
    short8 bl1 = *(const short8*)(cbl + eoff + 32);
    float  nv  = norms[l16];

    for (int n0 = 0; n0 < CB_N; n0 += 16) {
        const int nn = (n0 + 16) & (CB_N - 1);         // wrap: harmless reload of tile 0
        const int ne = nn * KDIM + eoff;
        short8 xh0 = *(const short8*)(cbh + ne);
        short8 xh1 = *(const short8*)(cbh + ne + 32);
        short8 xl0 = *(const short8*)(cbl + ne);
        short8 xl1 = *(const short8*)(cbl + ne + 32);
        float  xnv = norms[nn + l16];

        #pragma unroll
        for (int t = 0; t < 4; ++t) {
            f32x4 acc = {0.f, 0.f, 0.f, 0.f};
            acc = __builtin_amdgcn_mfma_f32_16x16x32_bf16(ah[t][0], bh0, acc, 0, 0, 0);
            acc = __builtin_amdgcn_mfma_f32_16x16x32_bf16(al[t][0], bh0, acc, 0, 0, 0);
            acc = __builtin_amdgcn_mfma_f32_16x16x32_bf16(ah[t][0], bl0, acc, 0, 0, 0);
            acc = __builtin_amdgcn_mfma_f32_16x16x32_bf16(ah[t][1], bh1, acc, 0, 0, 0);
            acc = __builtin_amdgcn_mfma_f32_16x16x32_bf16(al[t][1], bh1, acc, 0, 0, 0);
            acc = __builtin_amdgcn_mfma_f32_16x16x32_bf16(ah[t][1], bl1, acc, 0, 0, 0);
            // d[r] for query m = quad*4+r, code n = n0+l16
            #pragma unroll
            for (int r = 0; r < 4; ++r) {
                float d = acc[r] + nv;
                bool c = d < m1[t][r];
                m2[t][r] = fminf(m2[t][r], fmaxf(d, m1[t][r]));
                m1[t][r] = fminf(m1[t][r], d);
                i1[t][r] = c ? (n0 + l16) : i1[t][r];
            }
        }
        bh0 = xh0; bh1 = xh1; bl0 = xl0; bl1 = xl1; nv = xnv;
    }

    // ---- merge across the 16 lanes of each quad (n-residues), first-index ties
    #pragma unroll
    for (int s = 1; s < 16; s <<= 1) {
        #pragma unroll
        for (int t = 0; t < 4; ++t)
            #pragma unroll
            for (int r = 0; r < 4; ++r) {
                float o1 = __shfl_xor(m1[t][r], s, 64);
                int   oi = __shfl_xor(i1[t][r], s, 64);
                float o2 = __shfl_xor(m2[t][r], s, 64);
                float hi = fmaxf(m1[t][r], o1);
                m2[t][r] = fminf(fminf(m2[t][r], o2), hi);
                if (o1 < m1[t][r] || (o1 == m1[t][r] && oi < i1[t][r])) {
                    m1[t][r] = o1; i1[t][r] = oi;
                }
            }
    }

    // ---- owner lanes (l16==0): publish idx, loss partial, flags
    if (l16 == 0) {
        float lsum = 0.0f;
        #pragma unroll
        for (int t = 0; t < 4; ++t)
            #pragma unroll
            for (int r = 0; r < 4; ++r) {
                int ql = t * 16 + quad * 4 + r;
                idx_s[w][ql] = i1[t][r];
                lsum += m1[t][r] + zn_s[w][ql];
                if (m2[t][r] - m1[t][r] < TAU) {
                    int pos = atomicAdd(flag_cnt, 1);
                    if (pos < FCAP) {
                        flag_q[pos]   = qb + ql;
                        flag_m1[pos]  = m1[t][r];
                        flag_idx[pos] = i1[t][r];
                    }
                }
            }
        atomicAdd(loss_acc, lsum);
    }
    __syncthreads();

    // ---- epilogue: lane L owns query hw0+L; load its code row, coalesced store
    const int myidx = idx_s[w][lane];
    const float4* row = (const float4*)(cb + (size_t)myidx * KDIM);
    float* op = out + 1 + (size_t)b * CHW + hw0 + lane;
    #pragma unroll
    for (int k4 = 0; k4 < 16; ++k4) {
        float4 v = row[k4];
        op[(size_t)(k4 * 4 + 0) * HWD] = v.x;
        op[(size_t)(k4 * 4 + 1) * HWD] = v.y;
        op[(size_t)(k4 * 4 + 2) * HWD] = v.z;
        op[(size_t)(k4 * 4 + 3) * HWD] = v.w;
    }
}

// ---------------- fix: exact fp32 re-rank for flagged queries + finalize ----
__global__ void vq_fix(const float* __restrict__ z,
                       const float* __restrict__ cb,
                       float* __restrict__ out,
                       float* __restrict__ loss_acc,
                       const int* __restrict__ flag_q,
                       const float* __restrict__ flag_m1,
                       const int* __restrict__ flag_idx,
                       const int* __restrict__ flag_cnt,
                       int* __restrict__ done_cnt) {
    const int w    = threadIdx.x >> 6;
    const int lane = threadIdx.x & 63;
    const int gw   = blockIdx.x * 4 + w;
    const int NW   = gridDim.x * 4;

    int n = *flag_cnt;
    if (n > FCAP) n = FCAP;

    for (int f = gw; f < n; f += NW) {
        const int   q   = flag_q[f];
        const float m1o = flag_m1[f];
        const int   io  = flag_idx[f];
        const int   b   = q >> 12;
        const int   hw  = q & 4095;

        // broadcast-load z (all lanes same addresses)
        float zv[KDIM];
        float znorm = 0.0f;
        #pragma unroll
        for (int k = 0; k < KDIM; ++k) {
            zv[k] = z[(size_t)b * CHW + (size_t)k * HWD + hw];
            znorm = fmaf(zv[k], zv[k], znorm);
        }
        // exact distances, 16 codes per lane
        float best = 3.4e38f; int bj = 0;
        for (int i = 0; i < 16; ++i) {
            const int j = lane * 16 + i;
            const float4* row = (const float4*)(cb + (size_t)j * KDIM);
            float d = 0.0f;
            #pragma unroll
            for (int k4 = 0; k4 < 16; ++k4) {
                float4 v = row[k4];
                float t0 = zv[k4 * 4 + 0] - v.x;
                float t1 = zv[k4 * 4 + 1] - v.y;
                float t2 = zv[k4 * 4 + 2] - v.z;
                float t3 = zv[k4 * 4 + 3] - v.w;
                d = fmaf(t0, t0, d); d = fmaf(t1, t1, d);
                d = fmaf(t2, t2, d); d = fmaf(t3, t3, d);
            }
            if (d < best) { best = d; bj = j; }   // j increasing: first-min
        }
        #pragma unroll
        for (int s = 1; s < 64; s <<= 1) {
            float ob = __shfl_xor(best, s, 64);
            int   oj = __shfl_xor(bj, s, 64);
            if (ob < best || (ob == best && oj < bj)) { best = ob; bj = oj; }
        }
        if (bj != io) {
            // rewrite this query's output row; patch loss
            out[1 + (size_t)b * CHW + (size_t)lane * HWD + hw] = cb[(size_t)bj * KDIM + lane];
            if (lane == 0) atomicAdd(loss_acc, best - (m1o + znorm));
        }
    }

    __syncthreads();
    if (threadIdx.x == 0) {
        __threadfence();
        int old = atomicAdd(done_cnt, 1);
        if (old == (int)gridDim.x - 1) {
            float L = atomicAdd(loss_acc, 0.0f);   // coherent read
            out[0] = 1.25f * L / TOTALF;
        }
    }
}

extern "C" void kernel_launch(void* const* d_in, const int* in_sizes, int n_in,
                              void* d_out, int out_size, void* d_ws, size_t ws_size,
                              hipStream_t stream) {
    const float* z  = (const float*)d_in[0];
    const float* cb = (const float*)d_in[1];
    float* out      = (float*)d_out;
    char*  ws       = (char*)d_ws;

    float*          loss_acc = (float*)(ws + 0);
    int*            flag_cnt = (int*)(ws + 4);
    int*            done_cnt = (int*)(ws + 8);
    float*          norms    = (float*)(ws + 128);
    unsigned short* cbh      = (unsigned short*)(ws + 4224);
    unsigned short* cbl      = (unsigned short*)(ws + 135296);
    int*            flag_q   = (int*)(ws + 266368);
    float*          flag_m1  = (float*)(ws + 331904);
    int*            flag_idx = (int*)(ws + 397440);

    vq_prep<<<dim3(4), dim3(256), 0, stream>>>(cb, norms, cbh, cbl,
                                               loss_acc, flag_cnt, done_cnt);

    vq_main<<<dim3(NQ / 256), dim3(256), 0, stream>>>(z, cb, cbh, cbl, norms, out,
                                                      loss_acc, flag_q, flag_m1,
                                                      flag_idx, flag_cnt);

    vq_fix<<<dim3(32), dim3(256), 0, stream>>>(z, cb, out, loss_acc,
                                               flag_q, flag_m1, flag_idx,
                                               flag_cnt, done_cnt);
}

// Round 3
// 248.457 us; speedup vs baseline: 2.1080x; 1.0542x over previous
//
#include <hip/hip_runtime.h>

// VQ-VAE VectorQuantizer: bf16 split-MFMA distance + exact fp32 fallback.
// z: (32,64,64,64) NCHW fp32; codebook: (1024,64) fp32.
// d_out: [0]=loss, [1..]=z_q (NCHW).
//
// R3: block = 4 waves x same 64 queries; wave w = queries [32(w&1),+32) x
// codes [512(w>>1),+512). 8192 waves total (R2 had 2048 -> grid-capped at
// 2 waves/SIMD). TAU 3e-3 -> 2.5e-4 (R2 flag-overflowed FCAP -> 128us fix).

#define CB_N   1024
#define KDIM   64
#define HWD    4096
#define CHW    (KDIM * HWD)
#define NQ     131072
#define TOTALF 8388608.0f
#define TAU    2.5e-4f
#define FCAP   16384

typedef __attribute__((ext_vector_type(8))) short  short8;
typedef __attribute__((ext_vector_type(4))) float  f32x4;

__device__ __forceinline__ unsigned short bf16_rne(float f) {
    union { float f; unsigned u; } c; c.f = f;
    return (unsigned short)((c.u + 0x7FFFu + ((c.u >> 16) & 1u)) >> 16);
}
__device__ __forceinline__ float bf16_tof(unsigned short h) {
    union { unsigned u; float f; } c; c.u = ((unsigned)h) << 16; return c.f;
}

// ---------- ws layout (byte offsets) ----------
// 0: loss_acc  4: flag_cnt  8: done_cnt
// 128:    norms f32[1024]
// 4224:   cbh u16[1024*64]
// 135296: cbl u16[1024*64]
// 266368: flag_q i32[FCAP]  331904: flag_m1 f32[FCAP]  397440: flag_idx i32[FCAP]

// ---------------- prep: split codebook to bf16 hi/lo, norms, zero counters --
// 4096 threads: thread = (row j, 16-elem segment seg).
__global__ void vq_prep(const float* __restrict__ cb,
                        float* __restrict__ norms,
                        unsigned short* __restrict__ cbh,
                        unsigned short* __restrict__ cbl,
                        float* __restrict__ loss_acc,
                        int* __restrict__ flag_cnt,
                        int* __restrict__ done_cnt) {
    const int tid = blockIdx.x * 256 + threadIdx.x;
    if (tid == 0) *loss_acc = 0.0f;
    if (tid == 1) *flag_cnt = 0;
    if (tid == 2) *done_cnt = 0;
    const int j   = tid >> 2;
    const int seg = tid & 3;
    const float4* r4 = (const float4*)(cb + (size_t)j * KDIM + seg * 16);
    unsigned uh[8], ul[8];
    float s = 0.0f;
    #pragma unroll
    for (int i4 = 0; i4 < 4; ++i4) {
        float4 v = r4[i4];
        float vv[4] = {v.x, v.y, v.z, v.w};
        #pragma unroll
        for (int c = 0; c < 4; ++c) {
            float x = vv[c];
            s = fmaf(x, x, s);
            unsigned short h = bf16_rne(x);
            unsigned short l = bf16_rne(x - bf16_tof(h));
            const int p = i4 * 2 + (c >> 1);
            if ((c & 1) == 0) { uh[p] = h; ul[p] = l; }
            else { uh[p] |= ((unsigned)h) << 16; ul[p] |= ((unsigned)l) << 16; }
        }
    }
    unsigned* dh = (unsigned*)(cbh + (size_t)j * KDIM + seg * 16);
    unsigned* dl = (unsigned*)(cbl + (size_t)j * KDIM + seg * 16);
    ((uint4*)dh)[0] = make_uint4(uh[0], uh[1], uh[2], uh[3]);
    ((uint4*)dh)[1] = make_uint4(uh[4], uh[5], uh[6], uh[7]);
    ((uint4*)dl)[0] = make_uint4(ul[0], ul[1], ul[2], ul[3]);
    ((uint4*)dl)[1] = make_uint4(ul[4], ul[5], ul[6], ul[7]);
    // row-norm: 4 consecutive threads (4-aligned in wave) share row j
    s += __shfl_xor(s, 1, 64);
    s += __shfl_xor(s, 2, 64);
    if (seg == 0) norms[j] = s;
}

// ---------------- main ------------------------------------------------------
__global__ __launch_bounds__(256, 3) void vq_main(
        const float* __restrict__ z,
        const float* __restrict__ cb,
        const unsigned short* __restrict__ cbh,
        const unsigned short* __restrict__ cbl,
        const float* __restrict__ norms,
        float* __restrict__ out,
        float* __restrict__ loss_acc,
        int* __restrict__ flag_q,
        float* __restrict__ flag_m1,
        int* __restrict__ flag_idx,
        int* __restrict__ flag_cnt) {
    __shared__ float zn_s[64];
    __shared__ float m1_s[2][64];
    __shared__ float m2_s[2][64];
    __shared__ int   i1_s[2][64];
    __shared__ int   idx_s[64];

    const int tid  = threadIdx.x;
    const int w    = tid >> 6;
    const int lane = tid & 63;
    const int quad = lane >> 4;
    const int l16  = lane & 15;
    const int qh   = w & 1;            // query half
    const int chf  = w >> 1;           // code half
    const int qb   = blockIdx.x * 64;  // block's 64 queries (same batch b)
    const int b    = qb >> 12;
    const int hwq  = (qb & 4095) + qh * 32;

    // ---- stage A-frags for 2 query-tiles: z -> (-2z) split hi/lo + ||z||^2
    const float* zbase = z + (size_t)b * CHW + hwq;
    short8 ah[2][2], al[2][2];
    float znp[2] = {0.f, 0.f};
    #pragma unroll
    for (int t = 0; t < 2; ++t)
        #pragma unroll
        for (int ks = 0; ks < 2; ++ks)
            #pragma unroll
            for (int j = 0; j < 8; ++j) {
                float v = zbase[(size_t)(ks * 32 + quad * 8 + j) * HWD + t * 16 + l16];
                znp[t] = fmaf(v, v, znp[t]);
                float s = -2.0f * v;
                unsigned short h = bf16_rne(s);
                ah[t][ks][j] = (short)h;
                al[t][ks][j] = (short)bf16_rne(s - bf16_tof(h));
            }
    #pragma unroll
    for (int t = 0; t < 2; ++t) {
        znp[t] += __shfl_xor(znp[t], 16, 64);
        znp[t] += __shfl_xor(znp[t], 32, 64);
    }
    if (chf == 0 && lane < 16) {
        zn_s[qh * 32 + lane]      = znp[0];
        zn_s[qh * 32 + 16 + lane] = znp[1];
    }

    // ---- loop over this wave's 32 code-tiles, double-buffered B-frags
    float m1[2][4], m2[2][4];
    int   i1[2][4];
    #pragma unroll
    for (int t = 0; t < 2; ++t)
        #pragma unroll
        for (int r = 0; r < 4; ++r) { m1[t][r] = 3.4e38f; m2[t][r] = 3.4e38f; i1[t][r] = 0; }

    const int cb0 = chf << 9;          // 512*chf
    const int eb  = (cb0 + l16) * KDIM + quad * 8;
    short8 bh0 = *(const short8*)(cbh + eb);
    short8 bh1 = *(const short8*)(cbh + eb + 32);
    short8 bl0 = *(const short8*)(cbl + eb);
    short8 bl1 = *(const short8*)(cbl + eb + 32);
    float  nv  = norms[cb0 + l16];

    for (int n0 = 0; n0 < 512; n0 += 16) {
        const int nn = (n0 + 16) & 511;            // wrap: harmless reload
        const int ne = (cb0 + nn + l16) * KDIM + quad * 8;
        short8 xh0 = *(const short8*)(cbh + ne);
        short8 xh1 = *(const short8*)(cbh + ne + 32);
        short8 xl0 = *(const short8*)(cbl + ne);
        short8 xl1 = *(const short8*)(cbl + ne + 32);
        float  xnv = norms[cb0 + nn + l16];

        #pragma unroll
        for (int t = 0; t < 2; ++t) {
            f32x4 acc = {0.f, 0.f, 0.f, 0.f};
            acc = __builtin_amdgcn_mfma_f32_16x16x32_bf16(ah[t][0], bh0, acc, 0, 0, 0);
            acc = __builtin_amdgcn_mfma_f32_16x16x32_bf16(al[t][0], bh0, acc, 0, 0, 0);
            acc = __builtin_amdgcn_mfma_f32_16x16x32_bf16(ah[t][0], bl0, acc, 0, 0, 0);
            acc = __builtin_amdgcn_mfma_f32_16x16x32_bf16(ah[t][1], bh1, acc, 0, 0, 0);
            acc = __builtin_amdgcn_mfma_f32_16x16x32_bf16(al[t][1], bh1, acc, 0, 0, 0);
            acc = __builtin_amdgcn_mfma_f32_16x16x32_bf16(ah[t][1], bl1, acc, 0, 0, 0);
            #pragma unroll
            for (int r = 0; r < 4; ++r) {          // query m=quad*4+r, code cb0+n0+l16
                float d = acc[r] + nv;
                bool c = d < m1[t][r];
                m2[t][r] = fminf(m2[t][r], fmaxf(d, m1[t][r]));
                m1[t][r] = fminf(m1[t][r], d);
                i1[t][r] = c ? (cb0 + n0 + l16) : i1[t][r];
            }
        }
        bh0 = xh0; bh1 = xh1; bl0 = xl0; bl1 = xl1; nv = xnv;
    }

    // ---- merge across 16 lanes (code residues), first-index ties
    #pragma unroll
    for (int s = 1; s < 16; s <<= 1)
        #pragma unroll
        for (int t = 0; t < 2; ++t)
            #pragma unroll
            for (int r = 0; r < 4; ++r) {
                float o1 = __shfl_xor(m1[t][r], s, 64);
                int   oi = __shfl_xor(i1[t][r], s, 64);
                float o2 = __shfl_xor(m2[t][r], s, 64);
                float hi = fmaxf(m1[t][r], o1);
                m2[t][r] = fminf(fminf(m2[t][r], o2), hi);
                if (o1 < m1[t][r] || (o1 == m1[t][r] && oi < i1[t][r])) {
                    m1[t][r] = o1; i1[t][r] = oi;
                }
            }

    if (l16 == 0) {
        #pragma unroll
        for (int t = 0; t < 2; ++t)
            #pragma unroll
            for (int r = 0; r < 4; ++r) {
                const int q = qh * 32 + t * 16 + quad * 4 + r;
                m1_s[chf][q] = m1[t][r];
                m2_s[chf][q] = m2[t][r];
                i1_s[chf][q] = i1[t][r];
            }
    }
    __syncthreads();

    // ---- cross-half merge + flags + loss (wave 0, one thread per query)
    if (tid < 64) {
        const int q = tid;
        float a1 = m1_s[0][q], a2 = m2_s[0][q]; int ai = i1_s[0][q];
        float b1 = m1_s[1][q], b2 = m2_s[1][q]; int bi = i1_s[1][q];
        float m1f, m2f; int idxf;
        if (b1 < a1) { m1f = b1; idxf = bi; m2f = fminf(a1, fminf(a2, b2)); }
        else         { m1f = a1; idxf = ai; m2f = fminf(b1, fminf(a2, b2)); }
        idx_s[q] = idxf;
        if (m2f - m1f < TAU) {
            int pos = atomicAdd(flag_cnt, 1);
            if (pos < FCAP) {
                flag_q[pos]   = qb + q;
                flag_m1[pos]  = m1f;
                flag_idx[pos] = idxf;
            }
        }
        float lq = m1f + zn_s[q];
        #pragma unroll
        for (int s = 1; s < 64; s <<= 1) lq += __shfl_xor(lq, s, 64);
        if (tid == 0) atomicAdd(loss_acc, lq);
    }
    __syncthreads();

    // ---- epilogue: thread -> (query tid&63, channels [16*(tid>>6),+16))
    {
        const int q    = tid & 63;
        const int cseg = (tid >> 6) * 16;
        const int idx  = idx_s[q];
        const float4* row = (const float4*)(cb + (size_t)idx * KDIM + cseg);
        float* op = out + 1 + (size_t)b * CHW + (size_t)cseg * HWD + (qb & 4095) + q;
        #pragma unroll
        for (int i4 = 0; i4 < 4; ++i4) {
            float4 v = row[i4];
            op[(size_t)(i4 * 4 + 0) * HWD] = v.x;
            op[(size_t)(i4 * 4 + 1) * HWD] = v.y;
            op[(size_t)(i4 * 4 + 2) * HWD] = v.z;
            op[(size_t)(i4 * 4 + 3) * HWD] = v.w;
        }
    }
}

// ---------------- fix: exact fp32 re-rank for flagged queries + finalize ----
__global__ void vq_fix(const float* __restrict__ z,
                       const float* __restrict__ cb,
                       float* __restrict__ out,
                       float* __restrict__ loss_acc,
                       const int* __restrict__ flag_q,
                       const float* __restrict__ flag_m1,
                       const int* __restrict__ flag_idx,
                       const int* __restrict__ flag_cnt,
                       int* __restrict__ done_cnt) {
    const int w    = threadIdx.x >> 6;
    const int lane = threadIdx.x & 63;
    const int gw   = blockIdx.x * 4 + w;
    const int NW   = gridDim.x * 4;

    int n = *flag_cnt;
    if (n > FCAP) n = FCAP;

    for (int f = gw; f < n; f += NW) {
        const int   q   = flag_q[f];
        const float m1o = flag_m1[f];
        const int   io  = flag_idx[f];
        const int   b   = q >> 12;
        const int   hw  = q & 4095;

        float zv[KDIM];
        float znorm = 0.0f;
        #pragma unroll
        for (int k = 0; k < KDIM; ++k) {
            zv[k] = z[(size_t)b * CHW + (size_t)k * HWD + hw];
            znorm = fmaf(zv[k], zv[k], znorm);
        }
        float best = 3.4e38f; int bj = 0;
        for (int i = 0; i < 16; ++i) {
            const int j = lane * 16 + i;
            const float4* row = (const float4*)(cb + (size_t)j * KDIM);
            float d = 0.0f;
            #pragma unroll
            for (int k4 = 0; k4 < 16; ++k4) {
                float4 v = row[k4];
                float t0 = zv[k4 * 4 + 0] - v.x;
                float t1 = zv[k4 * 4 + 1] - v.y;
                float t2 = zv[k4 * 4 + 2] - v.z;
                float t3 = zv[k4 * 4 + 3] - v.w;
                d = fmaf(t0, t0, d); d = fmaf(t1, t1, d);
                d = fmaf(t2, t2, d); d = fmaf(t3, t3, d);
            }
            if (d < best) { best = d; bj = j; }
        }
        #pragma unroll
        for (int s = 1; s < 64; s <<= 1) {
            float ob = __shfl_xor(best, s, 64);
            int   oj = __shfl_xor(bj, s, 64);
            if (ob < best || (ob == best && oj < bj)) { best = ob; bj = oj; }
        }
        if (bj != io) {
            out[1 + (size_t)b * CHW + (size_t)lane * HWD + hw] = cb[(size_t)bj * KDIM + lane];
            if (lane == 0) atomicAdd(loss_acc, best - (m1o + znorm));
        }
    }

    __syncthreads();
    if (threadIdx.x == 0) {
        __threadfence();
        int old = atomicAdd(done_cnt, 1);
        if (old == (int)gridDim.x - 1) {
            float L = atomicAdd(loss_acc, 0.0f);
            out[0] = 1.25f * L / TOTALF;
        }
    }
}

extern "C" void kernel_launch(void* const* d_in, const int* in_sizes, int n_in,
                              void* d_out, int out_size, void* d_ws, size_t ws_size,
                              hipStream_t stream) {
    const float* z  = (const float*)d_in[0];
    const float* cb = (const float*)d_in[1];
    float* out      = (float*)d_out;
    char*  ws       = (char*)d_ws;

    float*          loss_acc = (float*)(ws + 0);
    int*            flag_cnt = (int*)(ws + 4);
    int*            done_cnt = (int*)(ws + 8);
    float*          norms    = (float*)(ws + 128);
    unsigned short* cbh      = (unsigned short*)(ws + 4224);
    unsigned short* cbl      = (unsigned short*)(ws + 135296);
    int*            flag_q   = (int*)(ws + 266368);
    float*          flag_m1  = (float*)(ws + 331904);
    int*            flag_idx = (int*)(ws + 397440);

    vq_prep<<<dim3(16), dim3(256), 0, stream>>>(cb, norms, cbh, cbl,
                                                loss_acc, flag_cnt, done_cnt);

    vq_main<<<dim3(NQ / 64), dim3(256), 0, stream>>>(z, cb, cbh, cbl, norms, out,
                                                     loss_acc, flag_q, flag_m1,
                                                     flag_idx, flag_cnt);

    vq_fix<<<dim3(256), dim3(256), 0, stream>>>(z, cb, out, loss_acc,
                                                flag_q, flag_m1, flag_idx,
                                                flag_cnt, done_cnt);
}

// Round 4
// 203.467 us; speedup vs baseline: 2.5741x; 1.2211x over previous
//
#include <hip/hip_runtime.h>

// VQ-VAE VectorQuantizer: bf16 split-MFMA distance + exact fp32 fallback.
// z: (32,64,64,64) NCHW fp32; codebook: (1024,64) fp32.
// d_out: [0]=loss, [1..]=z_q (NCHW).
//
// R4: B-fragments staged in LDS (8 chunks x 128 codes, XOR-swizzled rows for
// conflict-free ds_read_b128) instead of 1-deep global prefetch (R3 was
// latency-stalled on L2: MfmaUtil 13.5%, VALUBusy 30%, 155us vs 25us MFMA
// floor). Block = 4 waves x 128 queries; each wave covers all 1024 codes.

#define CB_N   1024
#define KDIM   64
#define HWD    4096
#define CHW    (KDIM * HWD)
#define NQ     131072
#define TOTALF 8388608.0f
#define TAU    2.5e-4f
#define FCAP   16384
#define CHUNK  128            // codes per LDS chunk
#define NCHUNK (CB_N / CHUNK)

typedef __attribute__((ext_vector_type(8))) short  short8;
typedef __attribute__((ext_vector_type(4))) float  f32x4;

__device__ __forceinline__ unsigned short bf16_rne(float f) {
    union { float f; unsigned u; } c; c.f = f;
    return (unsigned short)((c.u + 0x7FFFu + ((c.u >> 16) & 1u)) >> 16);
}
__device__ __forceinline__ float bf16_tof(unsigned short h) {
    union { unsigned u; float f; } c; c.u = ((unsigned)h) << 16; return c.f;
}

// ---------- ws layout (byte offsets) ----------
// 0: loss_acc  4: flag_cnt  8: done_cnt
// 128:    norms   f32[1024]
// 4224:   cbh_sw  u16[1024*64]   (XOR-swizzled rows)
// 135296: cbl_sw  u16[1024*64]   (XOR-swizzled rows)
// 266368: flag_q i32[FCAP]  331904: flag_m1 f32[FCAP]  397440: flag_idx i32[FCAP]

// ---------------- prep: bf16 hi/lo split, swizzled rows, norms, counters ----
// 1024 threads, thread j handles codebook row j.
// Row layout (shorts): cbX_sw[j*64 + ((s+j)&7)*8 .. +8) = elems [s*8, s*8+8).
__global__ void vq_prep(const float* __restrict__ cb,
                        float* __restrict__ norms,
                        unsigned short* __restrict__ cbh,
                        unsigned short* __restrict__ cbl,
                        float* __restrict__ loss_acc,
                        int* __restrict__ flag_cnt,
                        int* __restrict__ done_cnt) {
    const int j = blockIdx.x * 256 + threadIdx.x;
    if (j == 0) *loss_acc = 0.0f;
    if (j == 1) *flag_cnt = 0;
    if (j == 2) *done_cnt = 0;

    const float4* r4 = (const float4*)(cb + (size_t)j * KDIM);
    float s_norm = 0.0f;
    #pragma unroll
    for (int s = 0; s < 8; ++s) {          // segment of 8 elems
        float4 v0 = r4[s * 2 + 0];
        float4 v1 = r4[s * 2 + 1];
        float e[8] = {v0.x, v0.y, v0.z, v0.w, v1.x, v1.y, v1.z, v1.w};
        unsigned hh[4], ll[4];
        #pragma unroll
        for (int c = 0; c < 8; ++c) {
            float x = e[c];
            s_norm = fmaf(x, x, s_norm);
            unsigned short h = bf16_rne(x);
            unsigned short l = bf16_rne(x - bf16_tof(h));
            if ((c & 1) == 0) { hh[c >> 1] = h; ll[c >> 1] = l; }
            else { hh[c >> 1] |= ((unsigned)h) << 16; ll[c >> 1] |= ((unsigned)l) << 16; }
        }
        const int p = (s + j) & 7;
        *(uint4*)(cbh + (size_t)j * KDIM + p * 8) = make_uint4(hh[0], hh[1], hh[2], hh[3]);
        *(uint4*)(cbl + (size_t)j * KDIM + p * 8) = make_uint4(ll[0], ll[1], ll[2], ll[3]);
    }
    norms[j] = s_norm;
}

// ---------------- main ------------------------------------------------------
__global__ __launch_bounds__(256, 3) void vq_main(
        const float* __restrict__ z,
        const float* __restrict__ cb,
        const unsigned short* __restrict__ cbh,
        const unsigned short* __restrict__ cbl,
        const float* __restrict__ norms,
        float* __restrict__ out,
        float* __restrict__ loss_acc,
        int* __restrict__ flag_q,
        float* __restrict__ flag_m1,
        int* __restrict__ flag_idx,
        int* __restrict__ flag_cnt) {
    __shared__ float          norms_s[CB_N];            // 4 KB
    __shared__ unsigned short bh_s[CHUNK * KDIM];       // 16 KB
    __shared__ unsigned short bl_s[CHUNK * KDIM];       // 16 KB
    __shared__ float          zn_s[128];
    __shared__ int            idx_s[128];

    const int tid  = threadIdx.x;
    const int w    = tid >> 6;
    const int lane = tid & 63;
    const int quad = lane >> 4;
    const int l16  = lane & 15;
    const int qb   = blockIdx.x * 128;     // block's 128 queries (same batch b)
    const int b    = qb >> 12;
    const int hw0  = qb & 4095;

    // ---- stage all norms into LDS (256 float4 loads)
    {
        float4 nv4 = *(const float4*)(norms + tid * 4);
        *(float4*)(norms_s + tid * 4) = nv4;
    }

    // ---- stage A-frags: wave w owns queries [32w, 32w+32); 2 tiles of 16.
    // A layout: lane holds A[m=l16][k=quad*8+j] for tile t.
    const float* zbase = z + (size_t)b * CHW + hw0 + 32 * w;
    short8 ah[2][2], al[2][2];
    float znp[2] = {0.f, 0.f};
    #pragma unroll
    for (int t = 0; t < 2; ++t)
        #pragma unroll
        for (int ks = 0; ks < 2; ++ks)
            #pragma unroll
            for (int j = 0; j < 8; ++j) {
                float v = zbase[(size_t)(ks * 32 + quad * 8 + j) * HWD + t * 16 + l16];
                znp[t] = fmaf(v, v, znp[t]);
                float s = -2.0f * v;
                unsigned short h = bf16_rne(s);
                ah[t][ks][j] = (short)h;
                al[t][ks][j] = (short)bf16_rne(s - bf16_tof(h));
            }
    #pragma unroll
    for (int t = 0; t < 2; ++t) {
        znp[t] += __shfl_xor(znp[t], 16, 64);
        znp[t] += __shfl_xor(znp[t], 32, 64);
    }
    if (l16 == lane) {   // lanes 0..15
        zn_s[32 * w + l16]      = znp[0];
        zn_s[32 * w + 16 + l16] = znp[1];
    }

    // ---- chunk loop: stage 128 codes (hi+lo) into LDS, then 8 n-tiles
    float m1[2][4], m2[2][4];
    int   i1[2][4];
    #pragma unroll
    for (int t = 0; t < 2; ++t)
        #pragma unroll
        for (int r = 0; r < 4; ++r) { m1[t][r] = 3.4e38f; m2[t][r] = 3.4e38f; i1[t][r] = 0; }

    for (int ch = 0; ch < NCHUNK; ++ch) {
        if (ch) __syncthreads();           // previous chunk's reads done
        // linear copy: 16 KB each of cbh_sw/cbl_sw -> LDS (uint4 per thread x4)
        {
            const uint4* gh = (const uint4*)(cbh + (size_t)ch * CHUNK * KDIM);
            const uint4* gl = (const uint4*)(cbl + (size_t)ch * CHUNK * KDIM);
            uint4* sh = (uint4*)bh_s;
            uint4* sl = (uint4*)bl_s;
            #pragma unroll
            for (int k = 0; k < 4; ++k) sh[tid + k * 256] = gh[tid + k * 256];
            #pragma unroll
            for (int k = 0; k < 4; ++k) sl[tid + k * 256] = gl[tid + k * 256];
        }
        __syncthreads();

        #pragma unroll
        for (int t8 = 0; t8 < 8; ++t8) {
            const int crow = t8 * 16 + l16;            // chunk-local code row
            const float nv = norms_s[ch * CHUNK + crow];
            // swizzled segment offsets: s = ks*4+quad, p = (s + l16) & 7
            const int p0 = ((quad + l16) & 7) * 8;
            const int p1 = ((4 + quad + l16) & 7) * 8;
            const short8 bh0 = *(const short8*)(bh_s + crow * KDIM + p0);
            const short8 bh1 = *(const short8*)(bh_s + crow * KDIM + p1);
            const short8 bl0 = *(const short8*)(bl_s + crow * KDIM + p0);
            const short8 bl1 = *(const short8*)(bl_s + crow * KDIM + p1);
            const int code = ch * CHUNK + t8 * 16 + l16;

            #pragma unroll
            for (int t = 0; t < 2; ++t) {
                f32x4 acc = {nv, nv, nv, nv};
                acc = __builtin_amdgcn_mfma_f32_16x16x32_bf16(ah[t][0], bh0, acc, 0, 0, 0);
                acc = __builtin_amdgcn_mfma_f32_16x16x32_bf16(al[t][0], bh0, acc, 0, 0, 0);
                acc = __builtin_amdgcn_mfma_f32_16x16x32_bf16(ah[t][0], bl0, acc, 0, 0, 0);
                acc = __builtin_amdgcn_mfma_f32_16x16x32_bf16(ah[t][1], bh1, acc, 0, 0, 0);
                acc = __builtin_amdgcn_mfma_f32_16x16x32_bf16(al[t][1], bh1, acc, 0, 0, 0);
                acc = __builtin_amdgcn_mfma_f32_16x16x32_bf16(ah[t][1], bl1, acc, 0, 0, 0);
                #pragma unroll
                for (int r = 0; r < 4; ++r) {   // query m=quad*4+r, code=code
                    float d = acc[r];
                    bool c = d < m1[t][r];
                    m2[t][r] = fminf(m2[t][r], fmaxf(d, m1[t][r]));
                    m1[t][r] = fminf(m1[t][r], d);
                    i1[t][r] = c ? code : i1[t][r];
                }
            }
        }
    }

    // ---- merge across 16 lanes (code residues), first-index ties
    #pragma unroll
    for (int s = 1; s < 16; s <<= 1)
        #pragma unroll
        for (int t = 0; t < 2; ++t)
            #pragma unroll
            for (int r = 0; r < 4; ++r) {
                float o1 = __shfl_xor(m1[t][r], s, 64);
                int   oi = __shfl_xor(i1[t][r], s, 64);
                float o2 = __shfl_xor(m2[t][r], s, 64);
                float hi = fmaxf(m1[t][r], o1);
                m2[t][r] = fminf(fminf(m2[t][r], o2), hi);
                if (o1 < m1[t][r] || (o1 == m1[t][r] && oi < i1[t][r])) {
                    m1[t][r] = o1; i1[t][r] = oi;
                }
            }

    // ---- owners (l16==0): publish idx, flags, loss partial
    float lsum = 0.0f;
    if (l16 == 0) {
        #pragma unroll
        for (int t = 0; t < 2; ++t)
            #pragma unroll
            for (int r = 0; r < 4; ++r) {
                const int ql = 32 * w + t * 16 + quad * 4 + r;
                idx_s[ql] = i1[t][r];
                lsum += m1[t][r] + zn_s[ql];
                if (m2[t][r] - m1[t][r] < TAU) {
                    int pos = atomicAdd(flag_cnt, 1);
                    if (pos < FCAP) {
                        flag_q[pos]   = qb + ql;
                        flag_m1[pos]  = m1[t][r];
                        flag_idx[pos] = i1[t][r];
                    }
                }
            }
    }
    #pragma unroll
    for (int s = 1; s < 64; s <<= 1) lsum += __shfl_xor(lsum, s, 64);
    if (lane == 0) atomicAdd(loss_acc, lsum);
    __syncthreads();

    // ---- epilogue: thread -> (query tid&127, channels [32*(tid>>7),+32))
    {
        const int q  = tid & 127;
        const int cs = (tid >> 7) * 32;
        const int idx = idx_s[q];
        const float4* row = (const float4*)(cb + (size_t)idx * KDIM + cs);
        float* op = out + 1 + (size_t)b * CHW + (size_t)cs * HWD + hw0 + q;
        #pragma unroll
        for (int i4 = 0; i4 < 8; ++i4) {
            float4 v = row[i4];
            op[(size_t)(i4 * 4 + 0) * HWD] = v.x;
            op[(size_t)(i4 * 4 + 1) * HWD] = v.y;
            op[(size_t)(i4 * 4 + 2) * HWD] = v.z;
            op[(size_t)(i4 * 4 + 3) * HWD] = v.w;
        }
    }
}

// ---------------- fix: exact fp32 re-rank for flagged queries + finalize ----
__global__ void vq_fix(const float* __restrict__ z,
                       const float* __restrict__ cb,
                       float* __restrict__ out,
                       float* __restrict__ loss_acc,
                       const int* __restrict__ flag_q,
                       const float* __restrict__ flag_m1,
                       const int* __restrict__ flag_idx,
                       const int* __restrict__ flag_cnt,
                       int* __restrict__ done_cnt) {
    const int w    = threadIdx.x >> 6;
    const int lane = threadIdx.x & 63;
    const int gw   = blockIdx.x * 4 + w;
    const int NW   = gridDim.x * 4;

    int n = *flag_cnt;
    if (n > FCAP) n = FCAP;

    for (int f = gw; f < n; f += NW) {
        const int   q   = flag_q[f];
        const float m1o = flag_m1[f];
        const int   io  = flag_idx[f];
        const int   b   = q >> 12;
        const int   hw  = q & 4095;

        float zv[KDIM];
        float znorm = 0.0f;
        #pragma unroll
        for (int k = 0; k < KDIM; ++k) {
            zv[k] = z[(size_t)b * CHW + (size_t)k * HWD + hw];
            znorm = fmaf(zv[k], zv[k], znorm);
        }
        float best = 3.4e38f; int bj = 0;
        for (int i = 0; i < 16; ++i) {
            const int j = lane * 16 + i;
            const float4* row = (const float4*)(cb + (size_t)j * KDIM);
            float d = 0.0f;
            #pragma unroll
            for (int k4 = 0; k4 < 16; ++k4) {
                float4 v = row[k4];
                float t0 = zv[k4 * 4 + 0] - v.x;
                float t1 = zv[k4 * 4 + 1] - v.y;
                float t2 = zv[k4 * 4 + 2] - v.z;
                float t3 = zv[k4 * 4 + 3] - v.w;
                d = fmaf(t0, t0, d); d = fmaf(t1, t1, d);
                d = fmaf(t2, t2, d); d = fmaf(t3, t3, d);
            }
            if (d < best) { best = d; bj = j; }
        }
        #pragma unroll
        for (int s = 1; s < 64; s <<= 1) {
            float ob = __shfl_xor(best, s, 64);
            int   oj = __shfl_xor(bj, s, 64);
            if (ob < best || (ob == best && oj < bj)) { best = ob; bj = oj; }
        }
        if (bj != io) {
            out[1 + (size_t)b * CHW + (size_t)lane * HWD + hw] = cb[(size_t)bj * KDIM + lane];
            if (lane == 0) atomicAdd(loss_acc, best - (m1o + znorm));
        }
    }

    __syncthreads();
    if (threadIdx.x == 0) {
        __threadfence();
        int old = atomicAdd(done_cnt, 1);
        if (old == (int)gridDim.x - 1) {
            float L = atomicAdd(loss_acc, 0.0f);
            out[0] = 1.25f * L / TOTALF;
        }
    }
}

extern "C" void kernel_launch(void* const* d_in, const int* in_sizes, int n_in,
                              void* d_out, int out_size, void* d_ws, size_t ws_size,
                              hipStream_t stream) {
    const float* z  = (const float*)d_in[0];
    const float* cb = (const float*)d_in[1];
    float* out      = (float*)d_out;
    char*  ws       = (char*)d_ws;

    float*          loss_acc = (float*)(ws + 0);
    int*            flag_cnt = (int*)(ws + 4);
    int*            done_cnt = (int*)(ws + 8);
    float*          norms    = (float*)(ws + 128);
    unsigned short* cbh      = (unsigned short*)(ws + 4224);
    unsigned short* cbl      = (unsigned short*)(ws + 135296);
    int*            flag_q   = (int*)(ws + 266368);
    float*          flag_m1  = (float*)(ws + 331904);
    int*            flag_idx = (int*)(ws + 397440);

    vq_prep<<<dim3(4), dim3(256), 0, stream>>>(cb, norms, cbh, cbl,
                                               loss_acc, flag_cnt, done_cnt);

    vq_main<<<dim3(NQ / 128), dim3(256), 0, stream>>>(z, cb, cbh, cbl, norms, out,
                                                      loss_acc, flag_q, flag_m1,
                                                      flag_idx, flag_cnt);

    vq_fix<<<dim3(256), dim3(256), 0, stream>>>(z, cb, out, loss_acc,
                                                flag_q, flag_m1, flag_idx,
                                                flag_cnt, done_cnt);
}